// Round 4
// baseline (297.784 us; speedup 1.0000x reference)
//
#include <hip/hip_runtime.h>
#include <hip/hip_cooperative_groups.h>

namespace cg = cooperative_groups;

#define S 1024
#define B 32
#define D 1024
#define NCH 32          // s-chunks (phase B blocks per batch)
#define CH 32           // rows per chunk
#define RPW 8           // rows per wave
#define ECH 8           // e-chunks in phase A
#define EC 128          // e per chunk
#define DCH 32          // d per chunk in phase A

// ws layout (floats)
#define PG_OFF    0
#define LOG_OFF   (ECH * B * D)            // pg: 8*32*1024
#define MARR_OFF  (LOG_OFF + B * S)
#define LARR_OFF  (MARR_OFF + NCH * B)
#define PACC_OFF  (LARR_OFF + NCH * B)

__global__ __launch_bounds__(256, 4) void fused_all(
    const float* __restrict__ hid, const float* __restrict__ enc,
    const float* __restrict__ W, float* __restrict__ out, float* __restrict__ ws)
{
    const int tid  = threadIdx.x;
    const int bid  = blockIdx.x;
    const int lane = tid & 63;
    const int wid  = tid >> 6;

    float* pg     = ws + PG_OFF;
    float* logits = ws + LOG_OFF;
    float* marr   = ws + MARR_OFF;
    float* larr   = ws + LARR_OFF;
    float* pacc   = ws + PACC_OFF;

    __shared__ __align__(16) float sbuf[EC * 33];   // 16.5 KB: h_sh (A) / sacc (B) / shm,shl (C)
    __shared__ float4 g_sh[D / 4];                  // 4 KB
    __shared__ float sm[4], sl[4];

    cg::grid_group grid = cg::this_grid();

    // ---------- Phase A: pg[ec][b][d] = sum_{e in chunk} h[b,e] * W[e,d] ----------
    if (bid < ECH * DCH * (D / DCH) / (D / DCH) * 1 && bid < ECH * 32) {  // bid < 256
        const int ec = bid >> 5;               // 0..7
        const int dc = bid & 31;               // 0..31
        float* h_sh = sbuf;                    // [EC][33] padded
        #pragma unroll
        for (int k = 0; k < (EC * B) / 256; ++k) {
            int lin = tid + k * 256;
            int b = lin >> 7;                  // EC = 128
            int e = lin & (EC - 1);
            h_sh[e * 33 + b] = hid[b * D + ec * EC + e];
        }
        __syncthreads();
        const int dq = tid & 7;                // d-quad within 32-d chunk
        const int b  = tid >> 3;               // 0..31
        const float4* W4 = (const float4*)W;
        float4 a4 = {0.f, 0.f, 0.f, 0.f};
        for (int e = 0; e < EC; ++e) {
            float h  = h_sh[e * 33 + b];
            float4 w = W4[((size_t)(ec * EC + e) * D + dc * DCH) / 4 + dq];
            a4.x += h * w.x; a4.y += h * w.y; a4.z += h * w.z; a4.w += h * w.w;
        }
        ((float4*)(pg + (size_t)(ec * B + b) * D + dc * DCH))[dq] = a4;
    }

    grid.sync();

    // ---------- Phase B: flash logits + online softmax + weighted partials ----------
    const int c = bid >> 5;                    // s-chunk
    const int b = bid & 31;                    // batch

    {   // reduce pg -> g_sh (this batch's g row)
        float4 s4 = {0.f, 0.f, 0.f, 0.f};
        #pragma unroll
        for (int ec = 0; ec < ECH; ++ec) {
            float4 v = ((const float4*)(pg + (size_t)(ec * B + b) * D))[tid];
            s4.x += v.x; s4.y += v.y; s4.z += v.z; s4.w += v.w;
        }
        g_sh[tid] = s4;
    }
    __syncthreads();

    float4 gv[4];
    #pragma unroll
    for (int j = 0; j < 4; ++j) gv[j] = g_sh[j * 64 + lane];

    const float4* encb = (const float4*)enc;
    const int row0 = c * CH + wid * RPW;
    const size_t rstride = (size_t)B * (D / 4);
    size_t base = ((size_t)row0 * B + b) * (D / 4) + lane;

    float4 cur[4], nxt[4];
    #pragma unroll
    for (int j = 0; j < 4; ++j) cur[j] = encb[base + j * 64];

    float m = -3.0e38f, l = 0.f;
    float4 acc[4] = {{0,0,0,0},{0,0,0,0},{0,0,0,0},{0,0,0,0}};

    for (int i = 0; i < RPW; ++i) {
        if (i + 1 < RPW) {
            size_t nb = base + (size_t)(i + 1) * rstride;
            #pragma unroll
            for (int j = 0; j < 4; ++j) nxt[j] = encb[nb + j * 64];
        }
        float pd = 0.f;
        #pragma unroll
        for (int j = 0; j < 4; ++j)
            pd += cur[j].x * gv[j].x + cur[j].y * gv[j].y +
                  cur[j].z * gv[j].z + cur[j].w * gv[j].w;
        #pragma unroll
        for (int off = 1; off < 64; off <<= 1)
            pd += __shfl_xor(pd, off, 64);
        if (lane == 0) logits[b * S + row0 + i] = pd;
        float mn = fmaxf(m, pd);
        float sc = __expf(m - mn);
        float p  = __expf(pd - mn);
        l = l * sc + p;
        #pragma unroll
        for (int j = 0; j < 4; ++j) {
            acc[j].x = acc[j].x * sc + p * cur[j].x;
            acc[j].y = acc[j].y * sc + p * cur[j].y;
            acc[j].z = acc[j].z * sc + p * cur[j].z;
            acc[j].w = acc[j].w * sc + p * cur[j].w;
        }
        m = mn;
        #pragma unroll
        for (int j = 0; j < 4; ++j) cur[j] = nxt[j];
    }

    {   // merge 4 waves
        float4* sacc = (float4*)sbuf;          // [4][256]
        #pragma unroll
        for (int j = 0; j < 4; ++j) sacc[wid * 256 + j * 64 + lane] = acc[j];
        if (lane == 0) { sm[wid] = m; sl[wid] = l; }
        __syncthreads();
        float mg = fmaxf(fmaxf(sm[0], sm[1]), fmaxf(sm[2], sm[3]));
        float4 r = {0.f, 0.f, 0.f, 0.f};
        float lsum = 0.f;
        #pragma unroll
        for (int w = 0; w < 4; ++w) {
            float fw = __expf(sm[w] - mg);
            float4 a = sacc[w * 256 + wid * 64 + lane];
            r.x += a.x * fw; r.y += a.y * fw; r.z += a.z * fw; r.w += a.w * fw;
            lsum += sl[w] * fw;
        }
        ((float4*)pacc)[(size_t)(c * B + b) * (D / 4) + wid * 64 + lane] = r;
        if (tid == 0) { marr[c * B + b] = mg; larr[c * B + b] = lsum; }
    }

    grid.sync();

    // ---------- Phase C: combine partials -> reps; normalize logits -> alpha ----------
    if (bid < 4 * B) {
        const int q  = bid & 3;
        const int bb = bid >> 2;
        float* shm = sbuf;
        float* shl = sbuf + NCH;
        if (tid < NCH) { shm[tid] = marr[tid * B + bb]; shl[tid] = larr[tid * B + bb]; }
        __syncthreads();
        float mg = -3.0e38f;
        #pragma unroll
        for (int cc = 0; cc < NCH; ++cc) mg = fmaxf(mg, shm[cc]);
        const int d = q * 256 + tid;
        float lg = 0.f, racc = 0.f;
        #pragma unroll 4
        for (int cc = 0; cc < NCH; ++cc) {
            float fc = __expf(shm[cc] - mg);
            lg   += shl[cc] * fc;
            racc += pacc[(size_t)(cc * B + bb) * D + d] * fc;
        }
        float inv = 1.f / lg;
        out[bb * D + d] = racc * inv;                                     // reps [B,1,D]
        int s = q * 256 + tid;
        out[B * D + bb * S + s] = __expf(logits[bb * S + s] - mg) * inv;  // alpha [B,1,S]
    }
}

// ---------------- Fallback (non-cooperative) path: R3 kernels ----------------
__global__ __launch_bounds__(256) void fb_k1(const float* __restrict__ hid,
                                             const float* __restrict__ W,
                                             float* __restrict__ g) {
    const int tid = threadIdx.x;
    const int d   = blockIdx.x * 256 + tid;
    const int e0  = blockIdx.y * 64;
    __shared__ float4 sh[64 * 8];
    for (int k = 0; k < 8; ++k) {
        int lin = tid + k * 256;
        int b = lin >> 6, e = lin & 63;
        ((float*)sh)[e * 32 + b] = hid[b * D + e0 + e];
    }
    __syncthreads();
    float acc[32];
    #pragma unroll
    for (int b = 0; b < 32; ++b) acc[b] = 0.f;
    for (int e = 0; e < 64; ++e) {
        float w = W[(size_t)(e0 + e) * D + d];
        #pragma unroll
        for (int j = 0; j < 8; ++j) {
            float4 hv = sh[e * 8 + j];
            acc[4*j+0] += hv.x*w; acc[4*j+1] += hv.y*w; acc[4*j+2] += hv.z*w; acc[4*j+3] += hv.w*w;
        }
    }
    #pragma unroll
    for (int b = 0; b < 32; ++b) atomicAdd(&g[b * D + d], acc[b]);
}

__global__ __launch_bounds__(256) void fb_k2(const float* __restrict__ enc,
                                             const float* __restrict__ g,
                                             float* __restrict__ logits,
                                             float* __restrict__ marr,
                                             float* __restrict__ larr,
                                             float* __restrict__ pacc) {
    const int tid = threadIdx.x, lane = tid & 63, wid = tid >> 6;
    const int c = blockIdx.x, b = blockIdx.y;
    const float4* gp = (const float4*)(g + b * D);
    float4 gv[4];
    #pragma unroll
    for (int j = 0; j < 4; ++j) gv[j] = gp[j * 64 + lane];
    const float4* encb = (const float4*)enc;
    const int row0 = c * CH + wid * RPW;
    const size_t rstride = (size_t)B * (D / 4);
    size_t base = ((size_t)row0 * B + b) * (D / 4) + lane;
    float4 cur[4], nxt[4];
    #pragma unroll
    for (int j = 0; j < 4; ++j) cur[j] = encb[base + j * 64];
    float m = -3.0e38f, l = 0.f;
    float4 acc[4] = {{0,0,0,0},{0,0,0,0},{0,0,0,0},{0,0,0,0}};
    for (int i = 0; i < RPW; ++i) {
        if (i + 1 < RPW) {
            size_t nb = base + (size_t)(i + 1) * rstride;
            #pragma unroll
            for (int j = 0; j < 4; ++j) nxt[j] = encb[nb + j * 64];
        }
        float pd = 0.f;
        #pragma unroll
        for (int j = 0; j < 4; ++j)
            pd += cur[j].x*gv[j].x + cur[j].y*gv[j].y + cur[j].z*gv[j].z + cur[j].w*gv[j].w;
        #pragma unroll
        for (int off = 1; off < 64; off <<= 1) pd += __shfl_xor(pd, off, 64);
        if (lane == 0) logits[b * S + row0 + i] = pd;
        float mn = fmaxf(m, pd), sc = __expf(m - mn), p = __expf(pd - mn);
        l = l * sc + p;
        #pragma unroll
        for (int j = 0; j < 4; ++j) {
            acc[j].x = acc[j].x*sc + p*cur[j].x; acc[j].y = acc[j].y*sc + p*cur[j].y;
            acc[j].z = acc[j].z*sc + p*cur[j].z; acc[j].w = acc[j].w*sc + p*cur[j].w;
        }
        m = mn;
        #pragma unroll
        for (int j = 0; j < 4; ++j) cur[j] = nxt[j];
    }
    __shared__ float4 sacc[4][256];
    __shared__ float sm[4], sl[4];
    #pragma unroll
    for (int j = 0; j < 4; ++j) sacc[wid][j * 64 + lane] = acc[j];
    if (lane == 0) { sm[wid] = m; sl[wid] = l; }
    __syncthreads();
    float mg = fmaxf(fmaxf(sm[0], sm[1]), fmaxf(sm[2], sm[3]));
    float4 r = {0,0,0,0}; float lsum = 0.f;
    #pragma unroll
    for (int w = 0; w < 4; ++w) {
        float fw = __expf(sm[w] - mg);
        float4 a = sacc[w][wid * 64 + lane];
        r.x += a.x*fw; r.y += a.y*fw; r.z += a.z*fw; r.w += a.w*fw;
        lsum += sl[w] * fw;
    }
    ((float4*)pacc)[(size_t)(c * B + b) * (D/4) + wid * 64 + lane] = r;
    if (tid == 0) { marr[c * B + b] = mg; larr[c * B + b] = lsum; }
}

__global__ __launch_bounds__(256) void fb_k3(const float* __restrict__ logits,
                                             const float* __restrict__ marr,
                                             const float* __restrict__ larr,
                                             const float* __restrict__ pacc,
                                             float* __restrict__ out) {
    const int tid = threadIdx.x, q = blockIdx.x, b = blockIdx.y;
    __shared__ float shm[NCH], shl[NCH];
    if (tid < NCH) { shm[tid] = marr[tid * B + b]; shl[tid] = larr[tid * B + b]; }
    __syncthreads();
    float mg = -3.0e38f;
    #pragma unroll
    for (int c = 0; c < NCH; ++c) mg = fmaxf(mg, shm[c]);
    const int d = q * 256 + tid;
    float lg = 0.f, racc = 0.f;
    #pragma unroll 4
    for (int c = 0; c < NCH; ++c) {
        float fc = __expf(shm[c] - mg);
        lg += shl[c] * fc;
        racc += pacc[(size_t)(c * B + b) * D + d] * fc;
    }
    float inv = 1.f / lg;
    out[b * D + d] = racc * inv;
    int s = q * 256 + tid;
    out[B * D + b * S + s] = __expf(logits[b * S + s] - mg) * inv;
}

extern "C" void kernel_launch(void* const* d_in, const int* in_sizes, int n_in,
                              void* d_out, int out_size, void* d_ws, size_t ws_size,
                              hipStream_t stream) {
    const float* hid = (const float*)d_in[0];  // (2,B,H) flat == h[B, D]
    const float* enc = (const float*)d_in[1];  // (S,B,D)
    const float* W   = (const float*)d_in[2];  // (D,D)
    // d_in[3] = bias: per-b constant in logits -> cancels in softmax.

    float* out = (float*)d_out;
    float* ws  = (float*)d_ws;

    void* args[] = {(void*)&hid, (void*)&enc, (void*)&W, (void*)&out, (void*)&ws};
    hipError_t err = hipLaunchCooperativeKernel((void*)fused_all, dim3(NCH * B),
                                                dim3(256), args, 0, stream);
    if (err != hipSuccess) {
        // Fallback: 4-dispatch non-cooperative path (R3 structure).
        float* g      = ws + PACC_OFF + NCH * B * D;   // after coop buffers
        float* logits = g + B * D;
        float* marr   = logits + B * S;
        float* larr   = marr + NCH * B;
        float* pacc   = larr + NCH * B;
        hipMemsetAsync(g, 0, B * D * sizeof(float), stream);
        fb_k1<<<dim3(D / 256, 16), 256, 0, stream>>>(hid, W, g);
        fb_k2<<<dim3(NCH, B), 256, 0, stream>>>(enc, g, logits, marr, larr, pacc);
        fb_k3<<<dim3(4, B), 256, 0, stream>>>(logits, marr, larr, pacc, out);
    }
}

// Round 5
// 190.623 us; speedup vs baseline: 1.5622x; 1.5622x over previous
//
#include <hip/hip_runtime.h>

#define S 1024
#define B 32
#define D 1024
#define NCH 32          // s-chunks
#define CH 32           // rows per chunk
#define RPW 8           // rows per wave
#define ECH 8           // e-chunks in kA
#define EC 128          // e per chunk

// ws layout (floats)
#define PG_OFF   0                          // pg: ECH*B*D (1 MB)
#define LOG_OFF  (PG_OFF + ECH * B * D)     // logits: B*S
#define MARR_OFF (LOG_OFF + B * S)          // NCH*B
#define LARR_OFF (MARR_OFF + NCH * B)       // NCH*B
#define PACC_OFF (LARR_OFF + NCH * B)       // NCH*B*D (4 MB)
#define CNT_OFF  (PACC_OFF + NCH * B * D)   // B ints

// kA: pg[ec][b][d] = sum_{e in chunk ec} h[b,e] * W[e,d].  W read exactly once.
// Grid 256 = (ec 0..7) x (dc 0..31); 32-d slice per block, all 32 batches.
// Block 0 also zeroes the kB completion counters.
__global__ __launch_bounds__(256) void kA(const float* __restrict__ hid,
                                          const float* __restrict__ W,
                                          float* __restrict__ ws) {
    const int tid = threadIdx.x;
    if (blockIdx.x == 0 && tid < B) ((int*)(ws + CNT_OFF))[tid] = 0;

    const int ec = blockIdx.x >> 5;
    const int dc = blockIdx.x & 31;
    __shared__ float h_sh[EC * 33];          // [e][b], padded
    #pragma unroll
    for (int k = 0; k < (EC * B) / 256; ++k) {
        int lin = tid + k * 256;
        int b = lin >> 7;                    // EC = 128
        int e = lin & (EC - 1);
        h_sh[e * 33 + b] = hid[b * D + ec * EC + e];
    }
    __syncthreads();

    const int dq = tid & 7;                  // float4 index within 32-d slice
    const int b  = tid >> 3;
    const float4* W4 = (const float4*)W;
    float4 a4 = {0.f, 0.f, 0.f, 0.f};
    for (int e = 0; e < EC; ++e) {
        float h  = h_sh[e * 33 + b];
        float4 w = W4[((size_t)(ec * EC + e) * D + dc * 32) / 4 + dq];
        a4.x += h * w.x; a4.y += h * w.y; a4.z += h * w.z; a4.w += h * w.w;
    }
    float* pg = ws + PG_OFF;
    ((float4*)(pg + (size_t)(ec * B + b) * D + dc * 32))[dq] = a4;
}

// kB: reduce pg -> g[b] (LDS), flash logits + online softmax + weighted partials
// (enc read ONCE, held in registers), then last-block-per-batch combine.
__global__ __launch_bounds__(256) void kB(const float* __restrict__ enc,
                                          float* __restrict__ out,
                                          float* __restrict__ ws) {
    const int tid  = threadIdx.x;
    const int lane = tid & 63;
    const int wid  = tid >> 6;
    const int c    = blockIdx.x;
    const int b    = blockIdx.y;

    float* pg     = ws + PG_OFF;
    float* logits = ws + LOG_OFF;
    float* marr   = ws + MARR_OFF;
    float* larr   = ws + LARR_OFF;
    float* pacc   = ws + PACC_OFF;
    int*   cnt    = (int*)(ws + CNT_OFF);

    __shared__ float4 sacc[4 * 256];         // 16 KB; [0..255] doubles as g_sh
    __shared__ float sm[4], sl[4];
    __shared__ int sflag;

    // ---- g[b] = sum over 8 pg slices (L2-resident, 32 KB per block) ----
    {
        float4 s4 = {0.f, 0.f, 0.f, 0.f};
        #pragma unroll
        for (int ec = 0; ec < ECH; ++ec) {
            float4 v = ((const float4*)(pg + (size_t)(ec * B + b) * D))[tid];
            s4.x += v.x; s4.y += v.y; s4.z += v.z; s4.w += v.w;
        }
        sacc[tid] = s4;
    }
    __syncthreads();
    float4 gv[4];
    #pragma unroll
    for (int j = 0; j < 4; ++j) gv[j] = sacc[j * 64 + lane];
    __syncthreads();   // all gv reads done before sacc is reused below

    // ---- flash loop over this wave's RPW rows ----
    const float4* encb = (const float4*)enc;
    const int row0 = c * CH + wid * RPW;
    const size_t rstride = (size_t)B * (D / 4);
    size_t base = ((size_t)row0 * B + b) * (D / 4) + lane;

    float4 cur[4], nxt[4];
    #pragma unroll
    for (int j = 0; j < 4; ++j) cur[j] = encb[base + j * 64];

    float m = -3.0e38f, l = 0.f;
    float4 acc[4] = {{0,0,0,0},{0,0,0,0},{0,0,0,0},{0,0,0,0}};

    for (int i = 0; i < RPW; ++i) {
        if (i + 1 < RPW) {
            size_t nb = base + (size_t)(i + 1) * rstride;
            #pragma unroll
            for (int j = 0; j < 4; ++j) nxt[j] = encb[nb + j * 64];
        }
        float pd = 0.f;
        #pragma unroll
        for (int j = 0; j < 4; ++j)
            pd += cur[j].x * gv[j].x + cur[j].y * gv[j].y +
                  cur[j].z * gv[j].z + cur[j].w * gv[j].w;
        #pragma unroll
        for (int off = 1; off < 64; off <<= 1)
            pd += __shfl_xor(pd, off, 64);
        if (lane == 0) logits[b * S + row0 + i] = pd;
        float mn = fmaxf(m, pd);
        float sc = __expf(m - mn);
        float p  = __expf(pd - mn);
        l = l * sc + p;
        #pragma unroll
        for (int j = 0; j < 4; ++j) {
            acc[j].x = acc[j].x * sc + p * cur[j].x;
            acc[j].y = acc[j].y * sc + p * cur[j].y;
            acc[j].z = acc[j].z * sc + p * cur[j].z;
            acc[j].w = acc[j].w * sc + p * cur[j].w;
        }
        m = mn;
        #pragma unroll
        for (int j = 0; j < 4; ++j) cur[j] = nxt[j];
    }

    // ---- merge 4 waves -> block partial (m, l, acc) ----
    #pragma unroll
    for (int j = 0; j < 4; ++j) sacc[wid * 256 + j * 64 + lane] = acc[j];
    if (lane == 0) { sm[wid] = m; sl[wid] = l; }
    __syncthreads();
    {
        float mg = fmaxf(fmaxf(sm[0], sm[1]), fmaxf(sm[2], sm[3]));
        float4 r = {0.f, 0.f, 0.f, 0.f};
        float lsum = 0.f;
        #pragma unroll
        for (int w = 0; w < 4; ++w) {
            float fw = __expf(sm[w] - mg);
            float4 a = sacc[w * 256 + wid * 64 + lane];
            r.x += a.x * fw; r.y += a.y * fw; r.z += a.z * fw; r.w += a.w * fw;
            lsum += sl[w] * fw;
        }
        ((float4*)pacc)[(size_t)(c * B + b) * (D / 4) + wid * 64 + lane] = r;
        if (tid == 0) { marr[c * B + b] = mg; larr[c * B + b] = lsum; }
    }

    // ---- completion counter: last block of batch b combines ----
    __threadfence();
    if (tid == 0) {
        int old = __hip_atomic_fetch_add(&cnt[b], 1, __ATOMIC_ACQ_REL,
                                         __HIP_MEMORY_SCOPE_AGENT);
        sflag = (old == NCH - 1);
    }
    __syncthreads();
    if (!sflag) return;
    __threadfence();   // acquire: other blocks' pacc/marr/larr/logits now visible

    float* shm = (float*)sacc;          // reuse LDS
    float* shl = shm + NCH;
    if (tid < NCH) { shm[tid] = marr[tid * B + b]; shl[tid] = larr[tid * B + b]; }
    __syncthreads();
    float mg = -3.0e38f;
    #pragma unroll
    for (int cc = 0; cc < NCH; ++cc) mg = fmaxf(mg, shm[cc]);
    float4 racc = {0.f, 0.f, 0.f, 0.f};
    float lg = 0.f;
    #pragma unroll 4
    for (int cc = 0; cc < NCH; ++cc) {
        float fc = __expf(shm[cc] - mg);
        lg += shl[cc] * fc;
        float4 v = ((const float4*)pacc)[(size_t)(cc * B + b) * (D / 4) + tid];
        racc.x += v.x * fc; racc.y += v.y * fc; racc.z += v.z * fc; racc.w += v.w * fc;
    }
    float inv = 1.f / lg;
    float4 rep = {racc.x * inv, racc.y * inv, racc.z * inv, racc.w * inv};
    ((float4*)out)[b * (D / 4) + tid] = rep;                       // reps [B,1,D]
    float4 lo = ((const float4*)(logits + b * S))[tid];
    float4 al = {__expf(lo.x - mg) * inv, __expf(lo.y - mg) * inv,
                 __expf(lo.z - mg) * inv, __expf(lo.w - mg) * inv};
    ((float4*)(out + B * D))[b * (S / 4) + tid] = al;              // alpha [B,1,S]
}

extern "C" void kernel_launch(void* const* d_in, const int* in_sizes, int n_in,
                              void* d_out, int out_size, void* d_ws, size_t ws_size,
                              hipStream_t stream) {
    const float* hid = (const float*)d_in[0];  // (2,B,H) flat == h[B, D]
    const float* enc = (const float*)d_in[1];  // (S,B,D)
    const float* W   = (const float*)d_in[2];  // (D,D)
    // d_in[3] = bias: per-b constant in logits -> cancels in softmax.

    float* out = (float*)d_out;
    float* ws  = (float*)d_ws;

    kA<<<dim3(ECH * 32), 256, 0, stream>>>(hid, W, ws);
    kB<<<dim3(NCH, B), 256, 0, stream>>>(enc, out, ws);
}

// Round 6
// 44.380 us; speedup vs baseline: 6.7099x; 4.2953x over previous
//
#include <hip/hip_runtime.h>

#define S 1024
#define B 32
#define D 1024
#define NCH 64          // s-chunks
#define CH (S / NCH)    // 16 rows per block
#define RPW (CH / 4)    // 4 rows per wave
#define NPAIR (RPW / 2) // 2 pairs per wave
#define ECH 8           // e-chunks in kA
#define EC 128          // e per chunk

// ws layout (floats)
#define PG_OFF   0                          // pg: ECH*B*D (1 MB)
#define LOG_OFF  (PG_OFF + ECH * B * D)     // logits: B*S
#define MARR_OFF (LOG_OFF + B * S)          // NCH*B
#define LARR_OFF (MARR_OFF + NCH * B)       // NCH*B
#define PACC_OFF (LARR_OFF + NCH * B)       // NCH*B*D (8 MB)

// kA: pg[ec][b][d] = sum_{e in chunk ec} h[b,e] * W[e,d].  W read exactly once.
__global__ __launch_bounds__(256) void kA(const float* __restrict__ hid,
                                          const float* __restrict__ W,
                                          float* __restrict__ ws) {
    const int tid = threadIdx.x;
    const int ec = blockIdx.x >> 5;
    const int dc = blockIdx.x & 31;
    __shared__ float h_sh[EC * 33];          // [e][b], padded
    #pragma unroll
    for (int k = 0; k < (EC * B) / 256; ++k) {
        int lin = tid + k * 256;
        int b = lin >> 7;                    // EC = 128
        int e = lin & (EC - 1);
        h_sh[e * 33 + b] = hid[b * D + ec * EC + e];
    }
    __syncthreads();

    const int dq = tid & 7;                  // float4 index within 32-d slice
    const int b  = tid >> 3;
    const float4* W4 = (const float4*)W;
    float4 a4 = {0.f, 0.f, 0.f, 0.f};
    for (int e = 0; e < EC; ++e) {
        float h  = h_sh[e * 33 + b];
        float4 w = W4[((size_t)(ec * EC + e) * D + dc * 32) / 4 + dq];
        a4.x += h * w.x; a4.y += h * w.y; a4.z += h * w.z; a4.w += h * w.w;
    }
    float* pg = ws + PG_OFF;
    ((float4*)(pg + (size_t)(ec * B + b) * D + dc * 32))[dq] = a4;
}

// kB: reduce pg -> g[b] (LDS), flash over CH rows: pair-wise dots (dual shfl
// butterfly), online softmax, weighted partials. No fences, plain stores;
// inter-dispatch barrier provides visibility to kC.
__global__ __launch_bounds__(256) void kB(const float* __restrict__ enc,
                                          float* __restrict__ ws) {
    const int tid  = threadIdx.x;
    const int lane = tid & 63;
    const int wid  = tid >> 6;
    const int c    = blockIdx.x;
    const int b    = blockIdx.y;

    float* pg     = ws + PG_OFF;
    float* logits = ws + LOG_OFF;
    float* marr   = ws + MARR_OFF;
    float* larr   = ws + LARR_OFF;
    float* pacc   = ws + PACC_OFF;

    __shared__ float4 sacc[4 * 256];         // 16 KB; [0..255] doubles as g_sh
    __shared__ float sm[4], sl[4];

    // ---- g[b] = sum over 8 pg slices (L2-resident) ----
    {
        float4 s4 = {0.f, 0.f, 0.f, 0.f};
        #pragma unroll
        for (int ec = 0; ec < ECH; ++ec) {
            float4 v = ((const float4*)(pg + (size_t)(ec * B + b) * D))[tid];
            s4.x += v.x; s4.y += v.y; s4.z += v.z; s4.w += v.w;
        }
        sacc[tid] = s4;
    }
    __syncthreads();
    float4 gv[4];
    #pragma unroll
    for (int j = 0; j < 4; ++j) gv[j] = sacc[j * 64 + lane];
    __syncthreads();   // gv read before sacc reuse

    // ---- flash loop: NPAIR pairs of rows per wave ----
    const float4* encb = (const float4*)enc;
    const int row0 = c * CH + wid * RPW;
    const size_t rstride = (size_t)B * (D / 4);
    size_t base = ((size_t)row0 * B + b) * (D / 4) + lane;

    float4 cur[8], nxt[8];
    #pragma unroll
    for (int j = 0; j < 4; ++j) {
        cur[j]     = encb[base + j * 64];
        cur[4 + j] = encb[base + rstride + j * 64];
    }

    float m = -3.0e38f, l = 0.f;
    float4 acc[4] = {{0,0,0,0},{0,0,0,0},{0,0,0,0},{0,0,0,0}};

    #pragma unroll
    for (int p = 0; p < NPAIR; ++p) {
        if (p + 1 < NPAIR) {
            size_t nb = base + (size_t)(2 * (p + 1)) * rstride;
            #pragma unroll
            for (int j = 0; j < 4; ++j) {
                nxt[j]     = encb[nb + j * 64];
                nxt[4 + j] = encb[nb + rstride + j * 64];
            }
        }
        float pd0 = 0.f, pd1 = 0.f;
        #pragma unroll
        for (int j = 0; j < 4; ++j) {
            pd0 += cur[j].x * gv[j].x + cur[j].y * gv[j].y +
                   cur[j].z * gv[j].z + cur[j].w * gv[j].w;
            pd1 += cur[4+j].x * gv[j].x + cur[4+j].y * gv[j].y +
                   cur[4+j].z * gv[j].z + cur[4+j].w * gv[j].w;
        }
        #pragma unroll
        for (int off = 1; off < 64; off <<= 1) {   // two independent chains
            pd0 += __shfl_xor(pd0, off, 64);
            pd1 += __shfl_xor(pd1, off, 64);
        }
        if (lane == 0) {
            logits[b * S + row0 + 2 * p]     = pd0;
            logits[b * S + row0 + 2 * p + 1] = pd1;
        }
        float mn  = fmaxf(m, pd0);
        float sc0 = __expf(m - mn);
        float pA  = __expf(pd0 - mn);
        float mn2 = fmaxf(mn, pd1);
        float sc1 = __expf(mn - mn2);
        float pB  = __expf(pd1 - mn2);
        float s01 = sc0 * sc1;
        float a0  = pA * sc1;
        l = l * s01 + a0 + pB;
        #pragma unroll
        for (int j = 0; j < 4; ++j) {
            acc[j].x = acc[j].x * s01 + a0 * cur[j].x + pB * cur[4+j].x;
            acc[j].y = acc[j].y * s01 + a0 * cur[j].y + pB * cur[4+j].y;
            acc[j].z = acc[j].z * s01 + a0 * cur[j].z + pB * cur[4+j].z;
            acc[j].w = acc[j].w * s01 + a0 * cur[j].w + pB * cur[4+j].w;
        }
        m = mn2;
        #pragma unroll
        for (int j = 0; j < 8; ++j) cur[j] = nxt[j];
    }

    // ---- merge 4 waves -> block partial (m, l, acc) ----
    #pragma unroll
    for (int j = 0; j < 4; ++j) sacc[wid * 256 + j * 64 + lane] = acc[j];
    if (lane == 0) { sm[wid] = m; sl[wid] = l; }
    __syncthreads();
    float mg = fmaxf(fmaxf(sm[0], sm[1]), fmaxf(sm[2], sm[3]));
    float4 r = {0.f, 0.f, 0.f, 0.f};
    float lsum = 0.f;
    #pragma unroll
    for (int w = 0; w < 4; ++w) {
        float fw = __expf(sm[w] - mg);
        float4 a = sacc[w * 256 + wid * 64 + lane];
        r.x += a.x * fw; r.y += a.y * fw; r.z += a.z * fw; r.w += a.w * fw;
        lsum += sl[w] * fw;
    }
    ((float4*)pacc)[(size_t)(c * B + b) * (D / 4) + wid * 64 + lane] = r;
    if (tid == 0) { marr[c * B + b] = mg; larr[c * B + b] = lsum; }
}

// kC: combine NCH partials -> reps; normalize logits -> alpha.
__global__ __launch_bounds__(256) void kC(float* __restrict__ out,
                                          const float* __restrict__ ws) {
    const int tid = threadIdx.x;
    const int q   = blockIdx.x;
    const int b   = blockIdx.y;
    const float* logits = ws + LOG_OFF;
    const float* marr   = ws + MARR_OFF;
    const float* larr   = ws + LARR_OFF;
    const float* pacc   = ws + PACC_OFF;

    __shared__ float shm[NCH], shl[NCH];
    if (tid < NCH) { shm[tid] = marr[tid * B + b]; shl[tid] = larr[tid * B + b]; }
    __syncthreads();
    float mg = -3.0e38f;
    #pragma unroll
    for (int cc = 0; cc < NCH; ++cc) mg = fmaxf(mg, shm[cc]);
    const int d = q * 256 + tid;
    float lg = 0.f, racc = 0.f;
    #pragma unroll 4
    for (int cc = 0; cc < NCH; ++cc) {
        float fc = __expf(shm[cc] - mg);
        lg   += shl[cc] * fc;
        racc += pacc[(size_t)(cc * B + b) * D + d] * fc;
    }
    float inv = 1.f / lg;
    out[b * D + d] = racc * inv;                                   // reps [B,1,D]
    int s = q * 256 + tid;
    out[B * D + b * S + s] = __expf(logits[b * S + s] - mg) * inv; // alpha [B,1,S]
}

extern "C" void kernel_launch(void* const* d_in, const int* in_sizes, int n_in,
                              void* d_out, int out_size, void* d_ws, size_t ws_size,
                              hipStream_t stream) {
    const float* hid = (const float*)d_in[0];  // (2,B,H) flat == h[B, D]
    const float* enc = (const float*)d_in[1];  // (S,B,D)
    const float* W   = (const float*)d_in[2];  // (D,D)
    // d_in[3] = bias: per-b constant in logits -> cancels in softmax.

    float* out = (float*)d_out;
    float* ws  = (float*)d_ws;

    kA<<<dim3(ECH * 32), 256, 0, stream>>>(hid, W, ws);
    kB<<<dim3(NCH, B), 256, 0, stream>>>(enc, ws);
    kC<<<dim3(4, B), 256, 0, stream>>>(out, ws);
}

// Round 7
// 41.648 us; speedup vs baseline: 7.1500x; 1.0656x over previous
//
#include <hip/hip_runtime.h>

#define S 1024
#define B 32
#define D 1024
#define NCH 32          // s-chunks
#define CH (S / NCH)    // 32 rows per block
#define RPW (CH / 4)    // 8 rows per wave
#define NPAIR (RPW / 2) // 4 pairs per wave
#define ECH 8           // e-chunks in kA
#define EC 128          // e per chunk

// ws layout (floats)
#define PG_OFF   0                          // pg: ECH*B*D (1 MB)
#define LOG_OFF  (PG_OFF + ECH * B * D)     // logits: B*S
#define MARR_OFF (LOG_OFF + B * S)          // NCH*B
#define LARR_OFF (MARR_OFF + NCH * B)       // NCH*B
#define PACC_OFF (LARR_OFF + NCH * B)       // NCH*B*D (4 MB)

// kA: pg[ec][b][d] = sum_{e in chunk ec} h[b,e] * W[e,d].  W read exactly once.
__global__ __launch_bounds__(256) void kA(const float* __restrict__ hid,
                                          const float* __restrict__ W,
                                          float* __restrict__ ws) {
    const int tid = threadIdx.x;
    const int ec = blockIdx.x >> 5;
    const int dc = blockIdx.x & 31;
    __shared__ float h_sh[EC * 33];          // [e][b], padded
    #pragma unroll
    for (int k = 0; k < (EC * B) / 256; ++k) {
        int lin = tid + k * 256;
        int b = lin >> 7;                    // EC = 128
        int e = lin & (EC - 1);
        h_sh[e * 33 + b] = hid[b * D + ec * EC + e];
    }
    __syncthreads();

    const int dq = tid & 7;                  // float4 index within 32-d slice
    const int b  = tid >> 3;
    const float4* W4 = (const float4*)W;
    float4 a4 = {0.f, 0.f, 0.f, 0.f};
    for (int e = 0; e < EC; ++e) {
        float h  = h_sh[e * 33 + b];
        float4 w = W4[((size_t)(ec * EC + e) * D + dc * 32) / 4 + dq];
        a4.x += h * w.x; a4.y += h * w.y; a4.z += h * w.z; a4.w += h * w.w;
    }
    float* pg = ws + PG_OFF;
    ((float4*)(pg + (size_t)(ec * B + b) * D + dc * 32))[dq] = a4;
}

// kB: reduce pg -> g[b] (LDS), flash over CH rows: paired dots (dual shfl
// butterfly), online softmax, weighted partials. Fence-free; inter-dispatch
// barrier provides visibility to kC. 1024 blocks = 4/CU co-resident.
__global__ __launch_bounds__(256) void kB(const float* __restrict__ enc,
                                          float* __restrict__ ws) {
    const int tid  = threadIdx.x;
    const int lane = tid & 63;
    const int wid  = tid >> 6;
    const int c    = blockIdx.x;
    const int b    = blockIdx.y;

    float* pg     = ws + PG_OFF;
    float* logits = ws + LOG_OFF;
    float* marr   = ws + MARR_OFF;
    float* larr   = ws + LARR_OFF;
    float* pacc   = ws + PACC_OFF;

    __shared__ float4 sacc[4 * 256];         // 16 KB; [0..255] doubles as g_sh
    __shared__ float sm[4], sl[4];

    // ---- g[b] = sum over 8 pg slices (L2-resident) ----
    {
        float4 s4 = {0.f, 0.f, 0.f, 0.f};
        #pragma unroll
        for (int ec = 0; ec < ECH; ++ec) {
            float4 v = ((const float4*)(pg + (size_t)(ec * B + b) * D))[tid];
            s4.x += v.x; s4.y += v.y; s4.z += v.z; s4.w += v.w;
        }
        sacc[tid] = s4;
    }
    __syncthreads();
    float4 gv[4];
    #pragma unroll
    for (int j = 0; j < 4; ++j) gv[j] = sacc[j * 64 + lane];
    __syncthreads();   // gv read before sacc reuse

    // ---- flash loop: NPAIR pairs of rows per wave ----
    const float4* encb = (const float4*)enc;
    const int row0 = c * CH + wid * RPW;
    const size_t rstride = (size_t)B * (D / 4);
    size_t base = ((size_t)row0 * B + b) * (D / 4) + lane;

    float4 cur[8], nxt[8];
    #pragma unroll
    for (int j = 0; j < 4; ++j) {
        cur[j]     = encb[base + j * 64];
        cur[4 + j] = encb[base + rstride + j * 64];
    }

    float m = -3.0e38f, l = 0.f;
    float4 acc[4] = {{0,0,0,0},{0,0,0,0},{0,0,0,0},{0,0,0,0}};

    #pragma unroll
    for (int p = 0; p < NPAIR; ++p) {
        if (p + 1 < NPAIR) {
            size_t nb = base + (size_t)(2 * (p + 1)) * rstride;
            #pragma unroll
            for (int j = 0; j < 4; ++j) {
                nxt[j]     = encb[nb + j * 64];
                nxt[4 + j] = encb[nb + rstride + j * 64];
            }
        }
        float pd0 = 0.f, pd1 = 0.f;
        #pragma unroll
        for (int j = 0; j < 4; ++j) {
            pd0 += cur[j].x * gv[j].x + cur[j].y * gv[j].y +
                   cur[j].z * gv[j].z + cur[j].w * gv[j].w;
            pd1 += cur[4+j].x * gv[j].x + cur[4+j].y * gv[j].y +
                   cur[4+j].z * gv[j].z + cur[4+j].w * gv[j].w;
        }
        #pragma unroll
        for (int off = 1; off < 64; off <<= 1) {   // two independent chains
            pd0 += __shfl_xor(pd0, off, 64);
            pd1 += __shfl_xor(pd1, off, 64);
        }
        if (lane == 0) {
            logits[b * S + row0 + 2 * p]     = pd0;
            logits[b * S + row0 + 2 * p + 1] = pd1;
        }
        float mn  = fmaxf(m, pd0);
        float sc0 = __expf(m - mn);
        float pA  = __expf(pd0 - mn);
        float mn2 = fmaxf(mn, pd1);
        float sc1 = __expf(mn - mn2);
        float pB  = __expf(pd1 - mn2);
        float s01 = sc0 * sc1;
        float a0  = pA * sc1;
        l = l * s01 + a0 + pB;
        #pragma unroll
        for (int j = 0; j < 4; ++j) {
            acc[j].x = acc[j].x * s01 + a0 * cur[j].x + pB * cur[4+j].x;
            acc[j].y = acc[j].y * s01 + a0 * cur[j].y + pB * cur[4+j].y;
            acc[j].z = acc[j].z * s01 + a0 * cur[j].z + pB * cur[4+j].z;
            acc[j].w = acc[j].w * s01 + a0 * cur[j].w + pB * cur[4+j].w;
        }
        m = mn2;
        if (p + 1 < NPAIR) {
            #pragma unroll
            for (int j = 0; j < 8; ++j) cur[j] = nxt[j];
        }
    }

    // ---- merge 4 waves -> block partial (m, l, acc) ----
    #pragma unroll
    for (int j = 0; j < 4; ++j) sacc[wid * 256 + j * 64 + lane] = acc[j];
    if (lane == 0) { sm[wid] = m; sl[wid] = l; }
    __syncthreads();
    float mg = fmaxf(fmaxf(sm[0], sm[1]), fmaxf(sm[2], sm[3]));
    float4 r = {0.f, 0.f, 0.f, 0.f};
    float lsum = 0.f;
    #pragma unroll
    for (int w = 0; w < 4; ++w) {
        float fw = __expf(sm[w] - mg);
        float4 a = sacc[w * 256 + wid * 64 + lane];
        r.x += a.x * fw; r.y += a.y * fw; r.z += a.z * fw; r.w += a.w * fw;
        lsum += sl[w] * fw;
    }
    ((float4*)pacc)[(size_t)(c * B + b) * (D / 4) + tid] = r;
    if (tid == 0) { marr[c * B + b] = mg; larr[c * B + b] = lsum; }
}

// kC: combine NCH partials -> reps (float4, per-chunk exp factors cached in
// LDS); normalize logits -> alpha. Grid (4, B).
__global__ __launch_bounds__(256) void kC(float* __restrict__ out,
                                          const float* __restrict__ ws) {
    const int tid = threadIdx.x;
    const int q   = blockIdx.x;
    const int b   = blockIdx.y;
    const float* logits = ws + LOG_OFF;
    const float* marr   = ws + MARR_OFF;
    const float* larr   = ws + LARR_OFF;
    const float* pacc   = ws + PACC_OFF;

    __shared__ float shm[NCH], shl[NCH], shf[NCH];
    if (tid < NCH) { shm[tid] = marr[tid * B + b]; shl[tid] = larr[tid * B + b]; }
    __syncthreads();
    float mg = -3.0e38f;
    #pragma unroll
    for (int cc = 0; cc < NCH; ++cc) mg = fmaxf(mg, shm[cc]);
    if (tid < NCH) shf[tid] = __expf(shm[tid] - mg);
    __syncthreads();
    float lg = 0.f;
    #pragma unroll
    for (int cc = 0; cc < NCH; ++cc) lg += shl[cc] * shf[cc];
    const float inv = 1.f / lg;

    if (tid < 64) {            // reps quarter: 64 float4 = 256 floats of d
        const int d4 = q * 64 + tid;
        float4 racc = {0.f, 0.f, 0.f, 0.f};
        #pragma unroll 4
        for (int cc = 0; cc < NCH; ++cc) {
            float  fc = shf[cc];
            float4 v  = ((const float4*)pacc)[(size_t)(cc * B + b) * (D / 4) + d4];
            racc.x += v.x * fc; racc.y += v.y * fc;
            racc.z += v.z * fc; racc.w += v.w * fc;
        }
        float4 rep = {racc.x * inv, racc.y * inv, racc.z * inv, racc.w * inv};
        ((float4*)out)[b * (D / 4) + d4] = rep;                    // reps [B,1,D]
    }
    const int s = q * 256 + tid;
    out[B * D + b * S + s] = __expf(logits[b * S + s] - mg) * inv; // alpha [B,1,S]
}

extern "C" void kernel_launch(void* const* d_in, const int* in_sizes, int n_in,
                              void* d_out, int out_size, void* d_ws, size_t ws_size,
                              hipStream_t stream) {
    const float* hid = (const float*)d_in[0];  // (2,B,H) flat == h[B, D]
    const float* enc = (const float*)d_in[1];  // (S,B,D)
    const float* W   = (const float*)d_in[2];  // (D,D)
    // d_in[3] = bias: per-b constant in logits -> cancels in softmax.

    float* out = (float*)d_out;
    float* ws  = (float*)d_ws;

    kA<<<dim3(ECH * 32), 256, 0, stream>>>(hid, W, ws);
    kB<<<dim3(NCH, B), 256, 0, stream>>>(enc, ws);
    kC<<<dim3(4, B), 256, 0, stream>>>(out, ws);
}

// Round 8
// 41.405 us; speedup vs baseline: 7.1919x; 1.0059x over previous
//
#include <hip/hip_runtime.h>

#define S 1024
#define B 32
#define D 1024
#define NCH 32          // s-chunks
#define CH (S / NCH)    // 32 rows per block
#define RPW (CH / 4)    // 8 rows per wave
#define NPAIR (RPW / 2) // 4 pairs per wave
#define ECH 8           // e-chunks in kA
#define EC 128          // e per chunk

// ws layout (floats)
#define PG_OFF   0                          // pg: ECH*B*D (1 MB)
#define LOG_OFF  (PG_OFF + ECH * B * D)     // logits: B*S
#define MARR_OFF (LOG_OFF + B * S)          // NCH*B
#define LARR_OFF (MARR_OFF + NCH * B)       // NCH*B
#define PACC_OFF (LARR_OFF + NCH * B)       // NCH*B*D (4 MB)

// kA: pg[ec][b][d] = sum_{e in chunk ec} h[b,e] * W[e,d].  W read exactly once.
__global__ __launch_bounds__(256) void kA(const float* __restrict__ hid,
                                          const float* __restrict__ W,
                                          float* __restrict__ ws) {
    const int tid = threadIdx.x;
    const int ec = blockIdx.x >> 5;
    const int dc = blockIdx.x & 31;
    __shared__ float h_sh[EC * 33];          // [e][b], padded
    #pragma unroll
    for (int k = 0; k < (EC * B) / 256; ++k) {
        int lin = tid + k * 256;
        int b = lin >> 7;                    // EC = 128
        int e = lin & (EC - 1);
        h_sh[e * 33 + b] = hid[b * D + ec * EC + e];
    }
    __syncthreads();

    const int dq = tid & 7;                  // float4 index within 32-d slice
    const int b  = tid >> 3;
    const float4* W4 = (const float4*)W;
    float4 a4 = {0.f, 0.f, 0.f, 0.f};
    for (int e = 0; e < EC; ++e) {
        float h  = h_sh[e * 33 + b];
        float4 w = W4[((size_t)(ec * EC + e) * D + dc * 32) / 4 + dq];
        a4.x += h * w.x; a4.y += h * w.y; a4.z += h * w.z; a4.w += h * w.w;
    }
    float* pg = ws + PG_OFF;
    ((float4*)(pg + (size_t)(ec * B + b) * D + dc * 32))[dq] = a4;
}

// kB: flash logits + online softmax + weighted partials; enc read ONCE.
// Prologue: issue first TWO row-pairs of enc loads, THEN pg-reduce -> g_sh
// (single barrier) so HBM latency hides under the reduce. Fence-free.
__global__ __launch_bounds__(256) void kB(const float* __restrict__ enc,
                                          float* __restrict__ ws) {
    const int tid  = threadIdx.x;
    const int lane = tid & 63;
    const int wid  = tid >> 6;
    const int c    = blockIdx.x;
    const int b    = blockIdx.y;

    float* pg     = ws + PG_OFF;
    float* logits = ws + LOG_OFF;
    float* marr   = ws + MARR_OFF;
    float* larr   = ws + LARR_OFF;
    float* pacc   = ws + PACC_OFF;

    __shared__ float4 g_sh[256];             // 4 KB, read-only after barrier
    __shared__ float4 sacc[4 * 256];         // 16 KB, merge only
    __shared__ float sm[4], sl[4];

    // ---- issue first two pairs of enc rows (in flight during pg reduce) ----
    const float4* encb = (const float4*)enc;
    const int row0 = c * CH + wid * RPW;
    const size_t rstride = (size_t)B * (D / 4);
    size_t base = ((size_t)row0 * B + b) * (D / 4) + lane;

    float4 cur[8], nxt[8];
    #pragma unroll
    for (int j = 0; j < 4; ++j) {
        cur[j]     = encb[base + j * 64];
        cur[4 + j] = encb[base + rstride + j * 64];
    }
    #pragma unroll
    for (int j = 0; j < 4; ++j) {
        nxt[j]     = encb[base + 2 * rstride + j * 64];
        nxt[4 + j] = encb[base + 3 * rstride + j * 64];
    }

    // ---- g[b] = sum over 8 pg slices (L2-resident); single barrier ----
    {
        float4 s4 = {0.f, 0.f, 0.f, 0.f};
        #pragma unroll
        for (int ec = 0; ec < ECH; ++ec) {
            float4 v = ((const float4*)(pg + (size_t)(ec * B + b) * D))[tid];
            s4.x += v.x; s4.y += v.y; s4.z += v.z; s4.w += v.w;
        }
        g_sh[tid] = s4;
    }
    __syncthreads();
    float4 gv[4];
    #pragma unroll
    for (int j = 0; j < 4; ++j) gv[j] = g_sh[j * 64 + lane];

    // ---- flash loop: NPAIR pairs, rotate double-buffer ----
    float m = -3.0e38f, l = 0.f;
    float4 acc[4] = {{0,0,0,0},{0,0,0,0},{0,0,0,0},{0,0,0,0}};

    #pragma unroll
    for (int p = 0; p < NPAIR; ++p) {
        float pd0 = 0.f, pd1 = 0.f;
        #pragma unroll
        for (int j = 0; j < 4; ++j) {
            pd0 += cur[j].x * gv[j].x + cur[j].y * gv[j].y +
                   cur[j].z * gv[j].z + cur[j].w * gv[j].w;
            pd1 += cur[4+j].x * gv[j].x + cur[4+j].y * gv[j].y +
                   cur[4+j].z * gv[j].z + cur[4+j].w * gv[j].w;
        }
        #pragma unroll
        for (int off = 1; off < 64; off <<= 1) {   // two independent chains
            pd0 += __shfl_xor(pd0, off, 64);
            pd1 += __shfl_xor(pd1, off, 64);
        }
        if (lane == 0) {
            logits[b * S + row0 + 2 * p]     = pd0;
            logits[b * S + row0 + 2 * p + 1] = pd1;
        }
        float mn  = fmaxf(m, pd0);
        float sc0 = __expf(m - mn);
        float pA  = __expf(pd0 - mn);
        float mn2 = fmaxf(mn, pd1);
        float sc1 = __expf(mn - mn2);
        float pB  = __expf(pd1 - mn2);
        float s01 = sc0 * sc1;
        float a0  = pA * sc1;
        l = l * s01 + a0 + pB;
        #pragma unroll
        for (int j = 0; j < 4; ++j) {
            acc[j].x = acc[j].x * s01 + a0 * cur[j].x + pB * cur[4+j].x;
            acc[j].y = acc[j].y * s01 + a0 * cur[j].y + pB * cur[4+j].y;
            acc[j].z = acc[j].z * s01 + a0 * cur[j].z + pB * cur[4+j].z;
            acc[j].w = acc[j].w * s01 + a0 * cur[j].w + pB * cur[4+j].w;
        }
        m = mn2;
        if (p + 1 < NPAIR) {
            #pragma unroll
            for (int j = 0; j < 8; ++j) cur[j] = nxt[j];
        }
        if (p + 2 < NPAIR) {
            size_t nb = base + (size_t)(2 * (p + 2)) * rstride;
            #pragma unroll
            for (int j = 0; j < 4; ++j) {
                nxt[j]     = encb[nb + j * 64];
                nxt[4 + j] = encb[nb + rstride + j * 64];
            }
        }
    }

    // ---- merge 4 waves -> block partial (m, l, acc) ----
    #pragma unroll
    for (int j = 0; j < 4; ++j) sacc[wid * 256 + j * 64 + lane] = acc[j];
    if (lane == 0) { sm[wid] = m; sl[wid] = l; }
    __syncthreads();
    float mg = fmaxf(fmaxf(sm[0], sm[1]), fmaxf(sm[2], sm[3]));
    float4 r = {0.f, 0.f, 0.f, 0.f};
    float lsum = 0.f;
    #pragma unroll
    for (int w = 0; w < 4; ++w) {
        float fw = __expf(sm[w] - mg);
        float4 a = sacc[w * 256 + wid * 64 + lane];
        r.x += a.x * fw; r.y += a.y * fw; r.z += a.z * fw; r.w += a.w * fw;
        lsum += sl[w] * fw;
    }
    ((float4*)pacc)[(size_t)(c * B + b) * (D / 4) + tid] = r;
    if (tid == 0) { marr[c * B + b] = mg; larr[c * B + b] = lsum; }
}

// kC: combine NCH partials -> reps (float4, per-chunk exp factors cached in
// LDS); normalize logits -> alpha. Grid (4, B).
__global__ __launch_bounds__(256) void kC(float* __restrict__ out,
                                          const float* __restrict__ ws) {
    const int tid = threadIdx.x;
    const int q   = blockIdx.x;
    const int b   = blockIdx.y;
    const float* logits = ws + LOG_OFF;
    const float* marr   = ws + MARR_OFF;
    const float* larr   = ws + LARR_OFF;
    const float* pacc   = ws + PACC_OFF;

    __shared__ float shm[NCH], shl[NCH], shf[NCH];
    if (tid < NCH) { shm[tid] = marr[tid * B + b]; shl[tid] = larr[tid * B + b]; }
    __syncthreads();
    float mg = -3.0e38f;
    #pragma unroll
    for (int cc = 0; cc < NCH; ++cc) mg = fmaxf(mg, shm[cc]);
    if (tid < NCH) shf[tid] = __expf(shm[tid] - mg);
    __syncthreads();
    float lg = 0.f;
    #pragma unroll
    for (int cc = 0; cc < NCH; ++cc) lg += shl[cc] * shf[cc];
    const float inv = 1.f / lg;

    if (tid < 64) {            // reps quarter: 64 float4 = 256 floats of d
        const int d4 = q * 64 + tid;
        float4 racc = {0.f, 0.f, 0.f, 0.f};
        #pragma unroll 4
        for (int cc = 0; cc < NCH; ++cc) {
            float  fc = shf[cc];
            float4 v  = ((const float4*)pacc)[(size_t)(cc * B + b) * (D / 4) + d4];
            racc.x += v.x * fc; racc.y += v.y * fc;
            racc.z += v.z * fc; racc.w += v.w * fc;
        }
        float4 rep = {racc.x * inv, racc.y * inv, racc.z * inv, racc.w * inv};
        ((float4*)out)[b * (D / 4) + d4] = rep;                    // reps [B,1,D]
    }
    const int s = q * 256 + tid;
    out[B * D + b * S + s] = __expf(logits[b * S + s] - mg) * inv; // alpha [B,1,S]
}

extern "C" void kernel_launch(void* const* d_in, const int* in_sizes, int n_in,
                              void* d_out, int out_size, void* d_ws, size_t ws_size,
                              hipStream_t stream) {
    const float* hid = (const float*)d_in[0];  // (2,B,H) flat == h[B, D]
    const float* enc = (const float*)d_in[1];  // (S,B,D)
    const float* W   = (const float*)d_in[2];  // (D,D)
    // d_in[3] = bias: per-b constant in logits -> cancels in softmax.

    float* out = (float*)d_out;
    float* ws  = (float*)d_ws;

    kA<<<dim3(ECH * 32), 256, 0, stream>>>(hid, W, ws);
    kB<<<dim3(NCH, B), 256, 0, stream>>>(enc, ws);
    kC<<<dim3(4, B), 256, 0, stream>>>(out, ws);
}